// Round 2
// baseline (12069.493 us; speedup 1.0000x reference)
//
#include <hip/hip_runtime.h>

// VectorQuantizer: z [8,4096,256] f32, E [8192,256] f32.
// Must reproduce numpy-fp32 semantics bit-exactly:
//   dist[n,k] = fl32( fl32(A[n] - 2*dot32[n,k]) + C[k] ),  argmin_k first-index
// where A = np.sum(z**2,axis=1) (pairwise), C = np.sum(E**2,axis=1) (pairwise),
// dot32 = np.einsum fp32 (SSE sum-of-products: 4 mod-4 lane accumulators,
// unfused mul/add, combine (s0+s1)+(s2+s3)).
// ||z||^2 CANNOT be dropped: it quantizes distances to ulp(~256)=3e-5 creating
// fp32 ties whose first-index resolution the reference depends on.

#define KCODES 8192
#define DIM    256
#define NROWS  32768
#define MTILE  64
#define KTILE  64
#define DCHUNK 32
#define LPAD   68   // LDS row stride words: 272 B, 16B-aligned, <=2-way banks

// exact numpy pairwise fp32 sum of squares for 256 contiguous floats:
// pairwise(256) = pairwise(0..127) + pairwise(128..255); each 128-block:
// 8 accumulators r[j] over x[8i+j], combine ((r0+r1)+(r2+r3))+((r4+r5)+(r6+r7))
__device__ __forceinline__ float np_sumsq_256(const float* __restrict__ x)
{
    float blk[2];
#pragma unroll
    for (int b = 0; b < 2; ++b) {
        const float* p = x + 128 * b;
        float r[8];
        float4 v0 = *reinterpret_cast<const float4*>(p);
        float4 v1 = *reinterpret_cast<const float4*>(p + 4);
        r[0] = __fmul_rn(v0.x, v0.x); r[1] = __fmul_rn(v0.y, v0.y);
        r[2] = __fmul_rn(v0.z, v0.z); r[3] = __fmul_rn(v0.w, v0.w);
        r[4] = __fmul_rn(v1.x, v1.x); r[5] = __fmul_rn(v1.y, v1.y);
        r[6] = __fmul_rn(v1.z, v1.z); r[7] = __fmul_rn(v1.w, v1.w);
        for (int i = 8; i < 128; i += 8) {
            float4 w0 = *reinterpret_cast<const float4*>(p + i);
            float4 w1 = *reinterpret_cast<const float4*>(p + i + 4);
            r[0] = __fadd_rn(r[0], __fmul_rn(w0.x, w0.x));
            r[1] = __fadd_rn(r[1], __fmul_rn(w0.y, w0.y));
            r[2] = __fadd_rn(r[2], __fmul_rn(w0.z, w0.z));
            r[3] = __fadd_rn(r[3], __fmul_rn(w0.w, w0.w));
            r[4] = __fadd_rn(r[4], __fmul_rn(w1.x, w1.x));
            r[5] = __fadd_rn(r[5], __fmul_rn(w1.y, w1.y));
            r[6] = __fadd_rn(r[6], __fmul_rn(w1.z, w1.z));
            r[7] = __fadd_rn(r[7], __fmul_rn(w1.w, w1.w));
        }
        blk[b] = __fadd_rn(__fadd_rn(__fadd_rn(r[0], r[1]), __fadd_rn(r[2], r[3])),
                           __fadd_rn(__fadd_rn(r[4], r[5]), __fadd_rn(r[6], r[7])));
    }
    return __fadd_rn(blk[0], blk[1]);
}

__global__ void vq_rowsq(const float* __restrict__ X, float* __restrict__ out, int nrows)
{
    const int r = blockIdx.x * blockDim.x + threadIdx.x;
    if (r < nrows) out[r] = np_sumsq_256(X + (size_t)r * DIM);
}

__global__ __launch_bounds__(256, 2)
void vq_main(const float* __restrict__ z, const float* __restrict__ E,
             const float* __restrict__ A32, const float* __restrict__ C32,
             int* __restrict__ widx)
{
    __shared__ __align__(16) float zT[DIM][LPAD];    // [d][r] 69,632 B
    __shared__ __align__(16) float eT[DCHUNK][LPAD]; // [d][k]  8,704 B

    const int tid = threadIdx.x;
    const int tk = tid & 15;   // 4 codes each: local k = 4*tk+j
    const int tr = tid >> 4;   // 4 rows each: local r = 4*tr+i
    const int rowBase = blockIdx.x * MTILE;

    // stage z rows transposed into zT[d][r]
    for (int s = 0; s < 16; ++s) {
        int r  = (tid >> 4) + 16 * (s & 3);
        int d0 = 4 * (tid & 15) + 64 * (s >> 2);
        const float4 v = *reinterpret_cast<const float4*>(&z[(size_t)(rowBase + r) * DIM + d0]);
        zT[d0 + 0][r] = v.x; zT[d0 + 1][r] = v.y;
        zT[d0 + 2][r] = v.z; zT[d0 + 3][r] = v.w;
    }

    float Arow[4];
#pragma unroll
    for (int i = 0; i < 4; ++i) Arow[i] = A32[rowBase + 4 * tr + i];

    float m1[4]; int i1[4];
#pragma unroll
    for (int i = 0; i < 4; ++i) { m1[i] = 1e30f; i1[i] = 0; }

    for (int kt = 0; kt < KCODES; kt += KTILE) {
        // 4 SSE-lane accumulators per (row i, code j), indexed by d&3
        float acc[4][4][4];
#pragma unroll
        for (int i = 0; i < 4; ++i)
#pragma unroll
            for (int j = 0; j < 4; ++j)
#pragma unroll
                for (int L = 0; L < 4; ++L) acc[i][j][L] = 0.0f;

        float Cv[4];
#pragma unroll
        for (int j = 0; j < 4; ++j) Cv[j] = C32[kt + 4 * tk + j];

        for (int dc = 0; dc < DIM; dc += DCHUNK) {
            __syncthreads();   // protect eT from previous chunk's readers
            {
                const int kloc = tid >> 3;  // 0..31
                const int d4   = tid & 7;   // 0..7
#pragma unroll
                for (int h = 0; h < 2; ++h) {
                    const int kk = kloc + 32 * h;
                    const float4 v = *reinterpret_cast<const float4*>(
                        &E[(size_t)(kt + kk) * DIM + dc + 4 * d4]);
                    eT[4 * d4 + 0][kk] = v.x; eT[4 * d4 + 1][kk] = v.y;
                    eT[4 * d4 + 2][kk] = v.z; eT[4 * d4 + 3][kk] = v.w;
                }
            }
            __syncthreads();
#pragma unroll
            for (int d = 0; d < DCHUNK; ++d) {
                float zf[4], ef[4];
                *reinterpret_cast<float4*>(zf) =
                    *reinterpret_cast<const float4*>(&zT[dc + d][4 * tr]);
                *reinterpret_cast<float4*>(ef) =
                    *reinterpret_cast<const float4*>(&eT[d][4 * tk]);
                const int L = d & 3;   // compile-time after unroll
#pragma unroll
                for (int i = 0; i < 4; ++i)
#pragma unroll
                    for (int j = 0; j < 4; ++j)
                        acc[i][j][L] = __fadd_rn(acc[i][j][L], __fmul_rn(zf[i], ef[j]));
            }
        }

        // finalize scores for this k-tile exactly as numpy does
#pragma unroll
        for (int i = 0; i < 4; ++i) {
#pragma unroll
            for (int j = 0; j < 4; ++j) {
                const float dot = __fadd_rn(__fadd_rn(acc[i][j][0], acc[i][j][1]),
                                            __fadd_rn(acc[i][j][2], acc[i][j][3]));
                const float t    = __fsub_rn(Arow[i], 2.0f * dot); // *2 exact
                const float dist = __fadd_rn(t, Cv[j]);
                const int k = kt + 4 * tk + j;
                if (dist < m1[i]) { m1[i] = dist; i1[i] = k; }  // strict <: first index wins
            }
        }
    }

    // merge across the 16 tk lanes; lexicographic (value, index) for first-index ties
#pragma unroll
    for (int off = 1; off < 16; off <<= 1) {
#pragma unroll
        for (int i = 0; i < 4; ++i) {
            const float b1 = __shfl_xor(m1[i], off);
            const int  bi1 = __shfl_xor(i1[i], off);
            if (b1 < m1[i] || (b1 == m1[i] && bi1 < i1[i])) { m1[i] = b1; i1[i] = bi1; }
        }
    }

    if (tk == 0) {
#pragma unroll
        for (int i = 0; i < 4; ++i) widx[rowBase + 4 * tr + i] = i1[i];
    }
}

__global__ void vq_gather(const float* __restrict__ E, const int* __restrict__ widx,
                          float* __restrict__ out)
{
    const int gid = blockIdx.x * 256 + threadIdx.x;
    const int n  = gid >> 6;
    const int d4 = gid & 63;
    const int k = widx[n];
    reinterpret_cast<float4*>(out)[(size_t)n * 64 + d4] =
        reinterpret_cast<const float4*>(E)[(size_t)k * 64 + d4];
}

extern "C" void kernel_launch(void* const* d_in, const int* in_sizes, int n_in,
                              void* d_out, int out_size, void* d_ws, size_t ws_size,
                              hipStream_t stream)
{
    const float* zp = (const float*)d_in[0];
    const float* Ep = (const float*)d_in[1];
    float* out = (float*)d_out;
    char* ws = (char*)d_ws;

    float* A32 = (float*)ws;                        // 128 KB
    float* C32 = (float*)(ws + 131072);             //  32 KB
    int*   widx = (int*)(ws + 131072 + 32768);      // 128 KB

    vq_rowsq<<<NROWS / 256, 256, 0, stream>>>(zp, A32, NROWS);
    vq_rowsq<<<KCODES / 256, 256, 0, stream>>>(Ep, C32, KCODES);
    vq_main<<<NROWS / MTILE, 256, 0, stream>>>(zp, Ep, A32, C32, widx);
    vq_gather<<<NROWS * (DIM / 4) / 256, 256, 0, stream>>>(Ep, widx, out);
}

// Round 4
// 4143.502 us; speedup vs baseline: 2.9129x; 2.9129x over previous
//
#include <hip/hip_runtime.h>

// VectorQuantizer: z [8,4096,256] f32, E [8192,256] f32.
// numpy-fp32 semantics: dist[n,k] = fl(fl(A[n]-2*dot32[n,k])+C[k]), argmin first-index,
// dot32 = SSE sum-of-products (4 mod-4 lane accs, unfused, (s0+s1)+(s2+s3)).
// Two-phase: fp32-FMA GEMM finds candidate set (provable superset of exact argmin),
// exact SSE-emulated rescore picks the reference winner.

#define KCODES 8192
#define DIM    256
#define NROWS  32768
#define MTILE  64
#define KTILE  256
#define DCHUNK 32
#define CAP    16

// ---- exact numpy pairwise fp32 sum of squares (verified bit-exact round 2) ----
__device__ __forceinline__ float np_sumsq_256(const float* __restrict__ x)
{
    float blk[2];
#pragma unroll
    for (int b = 0; b < 2; ++b) {
        const float* p = x + 128 * b;
        float r[8];
        float4 v0 = *reinterpret_cast<const float4*>(p);
        float4 v1 = *reinterpret_cast<const float4*>(p + 4);
        r[0] = __fmul_rn(v0.x, v0.x); r[1] = __fmul_rn(v0.y, v0.y);
        r[2] = __fmul_rn(v0.z, v0.z); r[3] = __fmul_rn(v0.w, v0.w);
        r[4] = __fmul_rn(v1.x, v1.x); r[5] = __fmul_rn(v1.y, v1.y);
        r[6] = __fmul_rn(v1.z, v1.z); r[7] = __fmul_rn(v1.w, v1.w);
        for (int i = 8; i < 128; i += 8) {
            float4 w0 = *reinterpret_cast<const float4*>(p + i);
            float4 w1 = *reinterpret_cast<const float4*>(p + i + 4);
            r[0] = __fadd_rn(r[0], __fmul_rn(w0.x, w0.x));
            r[1] = __fadd_rn(r[1], __fmul_rn(w0.y, w0.y));
            r[2] = __fadd_rn(r[2], __fmul_rn(w0.z, w0.z));
            r[3] = __fadd_rn(r[3], __fmul_rn(w0.w, w0.w));
            r[4] = __fadd_rn(r[4], __fmul_rn(w1.x, w1.x));
            r[5] = __fadd_rn(r[5], __fmul_rn(w1.y, w1.y));
            r[6] = __fadd_rn(r[6], __fmul_rn(w1.z, w1.z));
            r[7] = __fadd_rn(r[7], __fmul_rn(w1.w, w1.w));
        }
        blk[b] = __fadd_rn(__fadd_rn(__fadd_rn(r[0], r[1]), __fadd_rn(r[2], r[3])),
                           __fadd_rn(__fadd_rn(r[4], r[5]), __fadd_rn(r[6], r[7])));
    }
    return __fadd_rn(blk[0], blk[1]);
}

__global__ void vq_rowsq(const float* __restrict__ X, float* __restrict__ out, int nrows)
{
    const int r = blockIdx.x * blockDim.x + threadIdx.x;
    if (r < nrows) out[r] = np_sumsq_256(X + (size_t)r * DIM);
}

// ---- phase 1: fp32-FMA GEMM + running-min + candidate collection ----
// t[k] = fmaf(-2, dot~, C[k]); append k when t <= runmin + W (W = 16 ulps of A).
__global__ __launch_bounds__(256, 3)
void vq_p1(const float* __restrict__ z, const float* __restrict__ E,
           const float* __restrict__ A32, const float* __restrict__ C32,
           int* __restrict__ counts, unsigned short* __restrict__ candg)
{
    __shared__ __align__(16) float zT[DCHUNK][68];        // [d][row] 8704 B
    __shared__ __align__(16) float eT[DCHUNK * 260];      // swizzled [d][code] 33280 B
    __shared__ int scnt[MTILE];
    __shared__ unsigned short scand[MTILE * CAP];

    const int tid = threadIdx.x;
    const int cg = tid & 31;   // code group: 8 codes
    const int rg = tid >> 5;   // row group: 8 rows
    const int rowBase = blockIdx.x * MTILE;

    if (tid < MTILE) scnt[tid] = 0;

    float Av[8], Wv[8], runm[8];
#pragma unroll
    for (int i = 0; i < 8; ++i) {
        Av[i] = A32[rowBase + rg * 8 + i];
        const unsigned eb = (__float_as_uint(Av[i]) >> 23) & 255u;
        Wv[i] = __uint_as_float((eb - 19u) << 23);   // 16 * 2^(ilogb(A)-23)
        runm[i] = 1e30f;
    }

    // swizzled read byte-offsets for this thread's two granules (codes cg*8..+7)
    const int g0 = 2 * cg, g1 = 2 * cg + 1;
    const int o0 = ((g0 ^ ((g0 >> 3) & 7)) << 4);
    const int o1 = ((g1 ^ ((g1 >> 3) & 7)) << 4);

    __syncthreads();

#pragma unroll 1
    for (int kt = 0; kt < KCODES; kt += KTILE) {
        float acc[8][8];
#pragma unroll
        for (int i = 0; i < 8; ++i)
#pragma unroll
            for (int j = 0; j < 8; ++j) acc[i][j] = 0.0f;

        float Cv[8];
#pragma unroll
        for (int j = 0; j < 8; ++j) Cv[j] = C32[kt + cg * 8 + j];

#pragma unroll 1
        for (int c = 0; c < DIM / DCHUNK; ++c) {
            const int dc = c * DCHUNK;
            __syncthreads();
            {   // stage z chunk: 64 rows x 32 d, transposed
                const int r = tid >> 2, q = tid & 3;
                const float* gz = &z[(size_t)(rowBase + r) * DIM + dc + 8 * q];
                const float4 v0 = *reinterpret_cast<const float4*>(gz);
                const float4 v1 = *reinterpret_cast<const float4*>(gz + 4);
                zT[8 * q + 0][r] = v0.x; zT[8 * q + 1][r] = v0.y;
                zT[8 * q + 2][r] = v0.z; zT[8 * q + 3][r] = v0.w;
                zT[8 * q + 4][r] = v1.x; zT[8 * q + 5][r] = v1.y;
                zT[8 * q + 6][r] = v1.z; zT[8 * q + 7][r] = v1.w;
            }
            {   // stage E chunk: 256 codes x 32 d, transposed + granule-swizzled
                const int d4 = tid & 7;
#pragma unroll
                for (int h = 0; h < 8; ++h) {
                    const int kk = (tid >> 3) + 32 * h;
                    const float4 v = *reinterpret_cast<const float4*>(
                        &E[(size_t)(kt + kk) * DIM + dc + 4 * d4]);
                    const int g = kk >> 2;
                    const int wb = ((g ^ ((g >> 3) & 7)) << 2) + (kk & 3);
                    eT[(4 * d4 + 0) * 260 + wb] = v.x;
                    eT[(4 * d4 + 1) * 260 + wb] = v.y;
                    eT[(4 * d4 + 2) * 260 + wb] = v.z;
                    eT[(4 * d4 + 3) * 260 + wb] = v.w;
                }
            }
            __syncthreads();

#pragma unroll 4
            for (int d = 0; d < DCHUNK; ++d) {
                const float4 za = *reinterpret_cast<const float4*>(&zT[d][rg * 8]);
                const float4 zb = *reinterpret_cast<const float4*>(&zT[d][rg * 8 + 4]);
                const char* eb = reinterpret_cast<const char*>(eT) + d * 1040;
                const float4 ea = *reinterpret_cast<const float4*>(eb + o0);
                const float4 eb4 = *reinterpret_cast<const float4*>(eb + o1);
                const float zf[8] = {za.x, za.y, za.z, za.w, zb.x, zb.y, zb.z, zb.w};
                const float ef[8] = {ea.x, ea.y, ea.z, ea.w, eb4.x, eb4.y, eb4.z, eb4.w};
#pragma unroll
                for (int i = 0; i < 8; ++i)
#pragma unroll
                    for (int j = 0; j < 8; ++j)
                        acc[i][j] = fmaf(zf[i], ef[j], acc[i][j]);
            }
        }

        // epilogue: scores, running min (half-wave = same rg), candidate append
#pragma unroll
        for (int i = 0; i < 8; ++i) {
            float t[8];
#pragma unroll
            for (int j = 0; j < 8; ++j) t[j] = fmaf(-2.0f, acc[i][j], Cv[j]);
            float tmin = fminf(fminf(fminf(t[0], t[1]), fminf(t[2], t[3])),
                               fminf(fminf(t[4], t[5]), fminf(t[6], t[7])));
            float wm = tmin;
#pragma unroll
            for (int off = 1; off < 32; off <<= 1) wm = fminf(wm, __shfl_xor(wm, off));
            runm[i] = fminf(runm[i], wm);
            const float thr = runm[i] + Wv[i];
            if (tmin <= thr) {
#pragma unroll
                for (int j = 0; j < 8; ++j) {
                    if (t[j] <= thr) {
                        const int idx = atomicAdd(&scnt[rg * 8 + i], 1);
                        if (idx < CAP)
                            scand[(rg * 8 + i) * CAP + idx] =
                                (unsigned short)(kt + cg * 8 + j);
                    }
                }
            }
        }
    }

    __syncthreads();
    if (tid < MTILE) {
        const int row = rowBase + tid;
        const int n = scnt[tid];
        counts[row] = n;
        const int m = n < CAP ? n : CAP;
        for (int c = 0; c < m; ++c) candg[(size_t)row * CAP + c] = scand[tid * CAP + c];
    }
}

// ---- phase 2: exact SSE-emulated rescore of candidates (lex-min = first index) ----
__global__ void vq_p2(const float* __restrict__ z, const float* __restrict__ E,
                      const float* __restrict__ A32, const float* __restrict__ C32,
                      const int* __restrict__ counts, const unsigned short* __restrict__ candg,
                      int* __restrict__ widx)
{
    const int lane = threadIdx.x & 63;
    const int row = blockIdx.x * 4 + (threadIdx.x >> 6);
    const int g16 = lane >> 2, L = lane & 3;
    const int cnt = counts[row];
    const bool full = (cnt <= 0) || (cnt > CAP);
    const int ncand = full ? KCODES : cnt;
    const float* zr = z + (size_t)row * DIM;
    const float Ar = A32[row];
    const float INF = __int_as_float(0x7f800000);

    float bd = INF; int bk = 0x7fffffff;
    for (int base = 0; base < ncand; base += 16) {
        const int ci = base + g16;
        const bool valid = ci < ncand;
        int kc = 0;
        if (valid) kc = full ? ci : (int)candg[(size_t)row * CAP + ci];
        float s = 0.0f;
        if (valid) {
            const float* er = E + (size_t)kc * DIM;
#pragma unroll 8
            for (int t = 0; t < 64; ++t) {
                const int d = 4 * t + L;
                s = __fadd_rn(s, __fmul_rn(zr[d], er[d]));
            }
        }
        const float a = __fadd_rn(s, __shfl_xor(s, 1));      // lane0: s0+s1, lane2: s2+s3
        const float dot = __fadd_rn(a, __shfl_xor(a, 2));    // lane0: (s0+s1)+(s2+s3)
        float dist = __fadd_rn(__fsub_rn(Ar, 2.0f * dot), C32[kc]);
        int kk = kc;
        if (!valid || L != 0) { dist = INF; kk = 0x7fffffff; }
        if (dist < bd || (dist == bd && kk < bk)) { bd = dist; bk = kk; }
    }
#pragma unroll
    for (int off = 1; off < 64; off <<= 1) {
        const float od = __shfl_xor(bd, off);
        const int ok = __shfl_xor(bk, off);
        if (od < bd || (od == bd && ok < bk)) { bd = od; bk = ok; }
    }
    if (lane == 0) widx[row] = bk;
}

__global__ void vq_gather(const float* __restrict__ E, const int* __restrict__ widx,
                          float* __restrict__ out)
{
    const int gid = blockIdx.x * 256 + threadIdx.x;
    const int n  = gid >> 6;
    const int d4 = gid & 63;
    const int k = widx[n];
    reinterpret_cast<float4*>(out)[(size_t)n * 64 + d4] =
        reinterpret_cast<const float4*>(E)[(size_t)k * 64 + d4];
}

extern "C" void kernel_launch(void* const* d_in, const int* in_sizes, int n_in,
                              void* d_out, int out_size, void* d_ws, size_t ws_size,
                              hipStream_t stream)
{
    const float* zp = (const float*)d_in[0];
    const float* Ep = (const float*)d_in[1];
    float* out = (float*)d_out;
    char* ws = (char*)d_ws;

    float* A32   = (float*)ws;                               // 131072 B
    float* C32   = (float*)(ws + 131072);                    //  32768 B
    int*   widx  = (int*)(ws + 163840);                      // 131072 B
    int*   counts = (int*)(ws + 294912);                     // 131072 B
    unsigned short* candg = (unsigned short*)(ws + 425984);  // 1048576 B

    vq_rowsq<<<NROWS / 256, 256, 0, stream>>>(zp, A32, NROWS);
    vq_rowsq<<<KCODES / 256, 256, 0, stream>>>(Ep, C32, KCODES);
    vq_p1<<<NROWS / MTILE, 256, 0, stream>>>(zp, Ep, A32, C32, counts, candg);
    vq_p2<<<NROWS / 4, 256, 0, stream>>>(zp, Ep, A32, C32, counts, candg, widx);
    vq_gather<<<NROWS * (DIM / 4) / 256, 256, 0, stream>>>(Ep, widx, out);
}

// Round 5
// 3513.040 us; speedup vs baseline: 3.4356x; 1.1795x over previous
//
#include <hip/hip_runtime.h>

// VectorQuantizer: z [8,4096,256] f32, E [8192,256] f32.
// numpy-fp32 semantics: dist[n,k] = fl(fl(A[n]-2*dot32[n,k])+C[k]), argmin first-index,
// dot32 = SSE sum-of-products (4 mod-4 lane accs, unfused, (s0+s1)+(s2+s3)).
// Phase 1: bf16 MFMA GEMM (hh term only; |err| <= 4.9e-5 worst-case << W) generates a
//   provable superset of the np argmin: all k with t~ <= min(t~) + 16*ulp(A).
//   Candidates final-filtered against the settled global min (fixes round-4 inflation).
// Phase 2: exact SSE-emulated rescore from LDS (stage z row + cand rows first, then
//   run the serial chains register/LDS-local — kills round-4's 36us/row load-stall).

#define KCODES 8192
#define DIM    256
#define NROWS  32768
#define BM     128     // rows per block (z persistent in LDS)
#define KT     256     // codes per outer iteration
#define CAPL   32      // LDS working candidate cap (pre-filter)
#define CAPG   16      // global candidate cap (post-filter)

typedef __attribute__((ext_vector_type(8))) short short8_t; // 8 bf16 (4 VGPR)
typedef __attribute__((ext_vector_type(4))) float f32x4_t;

__device__ __forceinline__ unsigned short bf16rn(float f)
{
    unsigned u = __float_as_uint(f);
    unsigned r = (u + 0x7fffu + ((u >> 16) & 1u)) >> 16;  // RN-even
    return (unsigned short)r;
}

// ---- exact numpy pairwise fp32 sum of squares (bit-exact, proven r2/r4) ----
__device__ __forceinline__ float np_sumsq_256(const float* __restrict__ x)
{
    float blk[2];
#pragma unroll
    for (int b = 0; b < 2; ++b) {
        const float* p = x + 128 * b;
        float r[8];
        float4 v0 = *reinterpret_cast<const float4*>(p);
        float4 v1 = *reinterpret_cast<const float4*>(p + 4);
        r[0] = __fmul_rn(v0.x, v0.x); r[1] = __fmul_rn(v0.y, v0.y);
        r[2] = __fmul_rn(v0.z, v0.z); r[3] = __fmul_rn(v0.w, v0.w);
        r[4] = __fmul_rn(v1.x, v1.x); r[5] = __fmul_rn(v1.y, v1.y);
        r[6] = __fmul_rn(v1.z, v1.z); r[7] = __fmul_rn(v1.w, v1.w);
        for (int i = 8; i < 128; i += 8) {
            float4 w0 = *reinterpret_cast<const float4*>(p + i);
            float4 w1 = *reinterpret_cast<const float4*>(p + i + 4);
            r[0] = __fadd_rn(r[0], __fmul_rn(w0.x, w0.x));
            r[1] = __fadd_rn(r[1], __fmul_rn(w0.y, w0.y));
            r[2] = __fadd_rn(r[2], __fmul_rn(w0.z, w0.z));
            r[3] = __fadd_rn(r[3], __fmul_rn(w0.w, w0.w));
            r[4] = __fadd_rn(r[4], __fmul_rn(w1.x, w1.x));
            r[5] = __fadd_rn(r[5], __fmul_rn(w1.y, w1.y));
            r[6] = __fadd_rn(r[6], __fmul_rn(w1.z, w1.z));
            r[7] = __fadd_rn(r[7], __fmul_rn(w1.w, w1.w));
        }
        blk[b] = __fadd_rn(__fadd_rn(__fadd_rn(r[0], r[1]), __fadd_rn(r[2], r[3])),
                           __fadd_rn(__fadd_rn(r[4], r[5]), __fadd_rn(r[6], r[7])));
    }
    return __fadd_rn(blk[0], blk[1]);
}

__global__ void vq_rowsq(const float* __restrict__ X, float* __restrict__ out, int nrows)
{
    const int r = blockIdx.x * blockDim.x + threadIdx.x;
    if (r < nrows) out[r] = np_sumsq_256(X + (size_t)r * DIM);
}

// ---- phase 1: bf16 MFMA GEMM + running-min + candidate collection ----
__global__ __launch_bounds__(256, 1)
void vq_p1(const float* __restrict__ z, const float* __restrict__ E,
           const float* __restrict__ A32, const float* __restrict__ C32,
           int* __restrict__ counts, unsigned short* __restrict__ candg)
{
    // zsh: [row][256] bf16, 16B-slot XOR-swizzled: slot' = slot ^ (row&7)  (64KB)
    __shared__ unsigned short zsh[BM * 256];
    // esh: [code][64] bf16 per d-chunk, same swizzle                        (32KB)
    __shared__ unsigned short esh[KT * 64];
    __shared__ float cbuf[KT];
    __shared__ float scandT[BM * CAPL];          // 16KB
    __shared__ unsigned short scandK[BM * CAPL]; // 8KB
    __shared__ int scnt[BM];
    __shared__ float rthr[2][BM];

    const int tid  = threadIdx.x;
    const int lane = tid & 63;
    const int wave = tid >> 6;
    const int wr = wave >> 1, wc = wave & 1;   // 2x2 wave grid: 64 rows x 128 codes
    const int l15 = lane & 15, l4 = lane >> 4;
    const int rowBase = blockIdx.x * BM;

    // ---- stage z once: 128 rows x 256 d, f32 -> bf16, swizzled ----
    {
        const int r = tid >> 1, hf = tid & 1;
        const float* zp = z + (size_t)(rowBase + r) * DIM + hf * 128;
#pragma unroll
        for (int i = 0; i < 32; ++i) {
            float4 v = reinterpret_cast<const float4*>(zp)[i];  // d = hf*128 + 4i
            unsigned h0 = bf16rn(v.x), h1 = bf16rn(v.y), h2 = bf16rn(v.z), h3 = bf16rn(v.w);
            const int slot = hf * 16 + (i >> 1);
            const int sub  = (i & 1) * 4;
            unsigned short* dst = &zsh[r * 256 + ((slot ^ (r & 7)) << 3) + sub];
            *reinterpret_cast<uint2*>(dst) = make_uint2(h0 | (h1 << 16), h2 | (h3 << 16));
        }
    }
    if (tid < BM) scnt[tid] = 0;

    // per-lane row bookkeeping: rows rl = 64*wr + 16*rf + 4*l4 + reg
    float runm[16], Wv[16];
#pragma unroll
    for (int rf = 0; rf < 4; ++rf)
#pragma unroll
        for (int reg = 0; reg < 4; ++reg) {
            const int rl = 64 * wr + 16 * rf + 4 * l4 + reg;
            const float a = A32[rowBase + rl];
            const unsigned eb = (__float_as_uint(a) >> 23) & 255u;
            Wv[rf * 4 + reg] = __uint_as_float((eb - 19u) << 23);   // 16 ulp(A)
            runm[rf * 4 + reg] = 1e30f;
        }
    __syncthreads();

#pragma unroll 1
    for (int kt = 0; kt < KCODES; kt += KT) {
        f32x4_t acc[4][8];
#pragma unroll
        for (int rf = 0; rf < 4; ++rf)
#pragma unroll
            for (int cf = 0; cf < 8; ++cf) acc[rf][cf] = (f32x4_t){0.f, 0.f, 0.f, 0.f};

#pragma unroll 1
        for (int c = 0; c < 4; ++c) {
            __syncthreads();   // prev chunk consumed; prev epilogue done (c==0)
            if (c == 0) cbuf[tid] = C32[kt + tid];
            // stage E chunk [256 codes][64 d]: f32 -> bf16, swizzled, coalesced
#pragma unroll
            for (int i = 0; i < 16; ++i) {
                const int gi = i * 256 + tid;
                const int code = gi >> 4;     // 0..255
                const int dp = gi & 15;       // float4 index within 64-d chunk
                float4 v = *reinterpret_cast<const float4*>(
                    &E[(size_t)(kt + code) * DIM + c * 64 + dp * 4]);
                unsigned h0 = bf16rn(v.x), h1 = bf16rn(v.y), h2 = bf16rn(v.z), h3 = bf16rn(v.w);
                const int slot = dp >> 1;
                const int sub  = (dp & 1) * 4;
                unsigned short* dst = &esh[code * 64 + ((slot ^ (code & 7)) << 3) + sub];
                *reinterpret_cast<uint2*>(dst) = make_uint2(h0 | (h1 << 16), h2 | (h3 << 16));
            }
            __syncthreads();
            // 2 k-steps of 32 d each
#pragma unroll
            for (int ks = 0; ks < 2; ++ks) {
                short8_t a[4], b[8];
#pragma unroll
                for (int rf = 0; rf < 4; ++rf) {
                    const int row = 64 * wr + 16 * rf + l15;     // A: row = lane&15
                    const int slot = 8 * c + 4 * ks + l4;        // k = 8*(lane>>4)+e
                    a[rf] = *reinterpret_cast<const short8_t*>(
                        &zsh[row * 256 + ((slot ^ (row & 7)) << 3)]);
                }
#pragma unroll
                for (int cf = 0; cf < 8; ++cf) {
                    const int code = 128 * wc + 16 * cf + l15;   // B: col = lane&15
                    const int slot = 4 * ks + l4;
                    b[cf] = *reinterpret_cast<const short8_t*>(
                        &esh[code * 64 + ((slot ^ (code & 7)) << 3)]);
                }
#pragma unroll
                for (int rf = 0; rf < 4; ++rf)
#pragma unroll
                    for (int cf = 0; cf < 8; ++cf)
                        acc[rf][cf] = __builtin_amdgcn_mfma_f32_16x16x32_bf16(
                            a[rf], b[cf], acc[rf][cf], 0, 0, 0);
            }
        }

        // ---- epilogue: t = C - 2*dot; wave-local running min; append ----
        // C/D layout: col = lane&15 (code), row = 4*(lane>>4)+reg  [m89-verified]
#pragma unroll
        for (int rf = 0; rf < 4; ++rf) {
#pragma unroll
            for (int reg = 0; reg < 4; ++reg) {
                float t[8];
#pragma unroll
                for (int cf = 0; cf < 8; ++cf)
                    t[cf] = fmaf(-2.0f, acc[rf][cf][reg], cbuf[128 * wc + 16 * cf + l15]);
                float m = fminf(fminf(fminf(t[0], t[1]), fminf(t[2], t[3])),
                                fminf(fminf(t[4], t[5]), fminf(t[6], t[7])));
                m = fminf(m, __shfl_xor(m, 1));
                m = fminf(m, __shfl_xor(m, 2));
                m = fminf(m, __shfl_xor(m, 4));
                m = fminf(m, __shfl_xor(m, 8));
                const int idx = rf * 4 + reg;
                runm[idx] = fminf(runm[idx], m);
                const float thr = runm[idx] + Wv[idx];
                const int rl = 64 * wr + 16 * rf + 4 * l4 + reg;
#pragma unroll
                for (int cf = 0; cf < 8; ++cf) {
                    if (t[cf] <= thr) {
                        const int ai = atomicAdd(&scnt[rl], 1);
                        if (ai < CAPL) {
                            scandT[rl * CAPL + ai] = t[cf];
                            scandK[rl * CAPL + ai] =
                                (unsigned short)(kt + 128 * wc + 16 * cf + l15);
                        }
                    }
                }
            }
        }
    }

    // wave-local thresholds -> LDS; min over the 2 code-partitions = global
    if (l15 == 0) {
#pragma unroll
        for (int rf = 0; rf < 4; ++rf)
#pragma unroll
            for (int reg = 0; reg < 4; ++reg)
                rthr[wc][64 * wr + 16 * rf + 4 * l4 + reg] =
                    runm[rf * 4 + reg] + Wv[rf * 4 + reg];
    }
    __syncthreads();
    if (tid < BM) {
        const int row = rowBase + tid;
        const float thrF = fminf(rthr[0][tid], rthr[1][tid]);
        const int n = scnt[tid];
        if (n > CAPL) { counts[row] = -1; }
        else {
            int m = 0;
            for (int i = 0; i < n; ++i) {
                if (scandT[tid * CAPL + i] <= thrF) {
                    if (m < CAPG) candg[(size_t)row * CAPG + m] = scandK[tid * CAPL + i];
                    ++m;
                }
            }
            counts[row] = (m <= CAPG) ? m : -1;
        }
    }
}

// ---- phase 2: exact SSE-emulated rescore; stage-then-chain (latency fix) ----
__global__ void vq_p2(const float* __restrict__ z, const float* __restrict__ E,
                      const float* __restrict__ A32, const float* __restrict__ C32,
                      const int* __restrict__ counts, const unsigned short* __restrict__ candg,
                      int* __restrict__ widx)
{
    __shared__ float zbuf[4][256];
    __shared__ float ebuf[4][8][264];   // +8 pad: 2-way banks for the 8 chain-quads
    const int lane = threadIdx.x & 63;
    const int w = threadIdx.x >> 6;
    const int row = blockIdx.x * 4 + w;
    const int cnt = counts[row];

    if (cnt == 1) {   // sole member of the provable superset IS the np argmin
        if (lane == 0) widx[row] = (int)candg[(size_t)row * CAPG];
        return;
    }
    {   // stage z row
        float4 v = *reinterpret_cast<const float4*>(&z[(size_t)row * DIM + lane * 4]);
        *reinterpret_cast<float4*>(&zbuf[w][lane * 4]) = v;
    }
    const bool full = (cnt < 0) || (cnt > CAPG);
    const int nc = full ? KCODES : cnt;
    const float Ar = A32[row];
    const float INF = __int_as_float(0x7f800000);
    float bd = INF; int bk = 0x7fffffff;
    const int g = lane >> 2, L = lane & 3;

    for (int base = 0; base < nc; base += 8) {
        int myc = 0x7fffffff;
        if (lane < 8 && base + lane < nc)
            myc = full ? (base + lane) : (int)candg[(size_t)row * CAPG + base + lane];
        // stage up to 8 candidate rows (vectorized, independent loads)
#pragma unroll
        for (int q = 0; q < 8; ++q) {
            const int kc = __shfl(myc, q);
            if (kc != 0x7fffffff) {
                float4 v = *reinterpret_cast<const float4*>(&E[(size_t)kc * DIM + lane * 4]);
                *reinterpret_cast<float4*>(&ebuf[w][q][lane * 4]) = v;
            }
        }
        asm volatile("s_waitcnt lgkmcnt(0)" ::: "memory");
        __builtin_amdgcn_sched_barrier(0);
        // exact SSE chains from LDS: lane L owns d == L (mod 4), serial order
        const int q = g & 7;
        float s = 0.0f;
#pragma unroll
        for (int t = 0; t < 64; ++t)
            s = __fadd_rn(s, __fmul_rn(zbuf[w][4 * t + L], ebuf[w][q][4 * t + L]));
        float a1  = __fadd_rn(s, __shfl_xor(s, 1));    // (s0+s1) on L==0
        float dot = __fadd_rn(a1, __shfl_xor(a1, 2));  // (s0+s1)+(s2+s3)
        int kc = __shfl(myc, q);
        const int kcs = (kc == 0x7fffffff) ? 0 : kc;
        float dist = __fadd_rn(__fsub_rn(Ar, 2.0f * dot), C32[kcs]);
        const bool act = (g < 8) && (L == 0) && (kc != 0x7fffffff);
        if (!act) { dist = INF; kc = 0x7fffffff; }
        if (dist < bd || (dist == bd && kc < bk)) { bd = dist; bk = kc; }
    }
#pragma unroll
    for (int off = 1; off < 64; off <<= 1) {
        const float od = __shfl_xor(bd, off);
        const int ok = __shfl_xor(bk, off);
        if (od < bd || (od == bd && ok < bk)) { bd = od; bk = ok; }
    }
    if (lane == 0) widx[row] = bk;
}

__global__ void vq_gather(const float* __restrict__ E, const int* __restrict__ widx,
                          float* __restrict__ out)
{
    const int gid = blockIdx.x * 256 + threadIdx.x;
    const int n  = gid >> 6;
    const int d4 = gid & 63;
    const int k = widx[n];
    reinterpret_cast<float4*>(out)[(size_t)n * 64 + d4] =
        reinterpret_cast<const float4*>(E)[(size_t)k * 64 + d4];
}

extern "C" void kernel_launch(void* const* d_in, const int* in_sizes, int n_in,
                              void* d_out, int out_size, void* d_ws, size_t ws_size,
                              hipStream_t stream)
{
    const float* zp = (const float*)d_in[0];
    const float* Ep = (const float*)d_in[1];
    float* out = (float*)d_out;
    char* ws = (char*)d_ws;

    float* A32    = (float*)ws;                              // 131072 B
    float* C32    = (float*)(ws + 131072);                   //  32768 B
    int*   widx   = (int*)(ws + 163840);                     // 131072 B
    int*   counts = (int*)(ws + 294912);                     // 131072 B
    unsigned short* candg = (unsigned short*)(ws + 425984);  // 32768*16*2 = 1 MB

    vq_rowsq<<<NROWS / 256, 256, 0, stream>>>(zp, A32, NROWS);
    vq_rowsq<<<KCODES / 256, 256, 0, stream>>>(Ep, C32, KCODES);
    vq_p1<<<NROWS / BM, 256, 0, stream>>>(zp, Ep, A32, C32, counts, candg);
    vq_p2<<<NROWS / 4, 256, 0, stream>>>(zp, Ep, A32, C32, counts, candg, widx);
    vq_gather<<<NROWS * (DIM / 4) / 256, 256, 0, stream>>>(Ep, widx, out);
}